// Round 6
// baseline (584.260 us; speedup 1.0000x reference)
//
#include <hip/hip_runtime.h>

// Problem constants (match reference)
#define BB 2048
#define HH 50
#define DD 400
#define D4 100            // DD/4 float4 per row
#define SS 285
#define CC 18
#define NCC 50
#define FILLV 1e-30f

static constexpr int BLOCK = 256;

// Output offsets (elements)
static constexpr size_t OFF1 = (size_t)BB * SS * DD;            // sub_weights
static constexpr size_t OFF2 = OFF1 + (size_t)BB * SS;          // cat_repr
static constexpr size_t OFF3 = OFF2 + (size_t)BB * CC * DD;     // cat_weights
static constexpr size_t OFF4 = OFF3 + (size_t)BB * CC;          // user_repr

// d_ws layout (floats)
#define WS_ETOT 0      // 400
#define WS_SCE  400    // 285  subcat_embed[s] . w_subcat[:D]
#define WS_SEW  688    // 285  subcat_embed[s] . w_cat[:D]
#define WS_CEDS 976    // 50   clicks_embed[k] . w_subcat[D:]
#define WS_CEDC 1026   // 50   clicks_embed[k] . w_cat[D:]
#define WS_CEW  1076   // 18   cat_embed[c] . w_cat[:D]

typedef float f4 __attribute__((ext_vector_type(4)));
typedef unsigned long long u64;

__device__ __forceinline__ float dot4(f4 a, f4 b) {
    return a.x * b.x + a.y * b.y + a.z * b.z + a.w * b.w;
}

// ---------------------------------------------------------------------------
// Pre-kernel: batch-invariant precomputation into d_ws
// ---------------------------------------------------------------------------
__global__ void hierec_pre(const float* __restrict__ subcat_embed,
                           const float* __restrict__ cat_embed,
                           const float* __restrict__ clicks_embed,
                           const float* __restrict__ w_subcat,
                           const float* __restrict__ w_cat,
                           float* __restrict__ ws)
{
    const int tid  = threadIdx.x;
    const int lane = tid & 63;
    const int wave = tid >> 6;
    const int wpb  = blockDim.x >> 6;
    const int gw   = blockIdx.x * wpb + wave;
    const int nw   = gridDim.x * wpb;

    for (int s = gw; s < SS; s += nw) {
        float p1 = 0.f, p2 = 0.f;
        for (int d = lane; d < DD; d += 64) {
            float v = subcat_embed[s * DD + d];
            p1 += v * w_subcat[d];
            p2 += v * w_cat[d];
        }
        for (int off = 32; off; off >>= 1) {
            p1 += __shfl_down(p1, off);
            p2 += __shfl_down(p2, off);
        }
        if (lane == 0) { ws[WS_SCE + s] = p1; ws[WS_SEW + s] = p2; }
    }
    if (blockIdx.x == 0) {
        for (int d = tid; d < DD; d += blockDim.x) {
            float a = 0.f;
            for (int s = 0; s < SS; ++s) a += subcat_embed[s * DD + d];
            ws[WS_ETOT + d] = a;
        }
    }
    if (blockIdx.x == 1) {
        for (int k = wave; k < HH; k += wpb) {
            float p1 = 0.f, p2 = 0.f;
            if (lane < NCC) {
                float v = clicks_embed[k * NCC + lane];
                p1 = v * w_subcat[DD + lane];
                p2 = v * w_cat[DD + lane];
            }
            for (int off = 32; off; off >>= 1) {
                p1 += __shfl_down(p1, off);
                p2 += __shfl_down(p2, off);
            }
            if (lane == 0) { ws[WS_CEDS + k] = p1; ws[WS_CEDC + k] = p2; }
        }
    }
    if (blockIdx.x == 2) {
        for (int c = wave; c < CC; c += wpb) {
            float p = 0.f;
            for (int d = lane; d < DD; d += 64) p += cat_embed[c * DD + d] * w_cat[d];
            for (int off = 32; off; off >>= 1) p += __shfl_down(p, off);
            if (lane == 0) ws[WS_CEW + c] = p;
        }
    }
}

// ---------------------------------------------------------------------------
// Main fused kernel: one block (256 thr) per batch element
// ---------------------------------------------------------------------------
__global__ __launch_bounds__(BLOCK, 8) void hierec_main(
    const float* __restrict__ vectors,      // [B,H,D]
    const int*   __restrict__ subcategory,  // [B,H]
    const int*   __restrict__ category,     // [B,H]
    const float* __restrict__ subcat_embed, // [S,D]
    const float* __restrict__ cat_embed,    // [C,D]
    const float* __restrict__ w_news,       // [D]
    const float* __restrict__ w_subcat,     // [D+NC]
    const float* __restrict__ w_cat,        // [D+NC]
    const float* __restrict__ pre,          // d_ws precomputed
    float* __restrict__ out)
{
    const int b    = blockIdx.x;
    const int tid  = threadIdx.x;
    const int lane = tid & 63;
    const int wave = tid >> 6;

    __shared__ f4     vt4L[D4];      // vtot
    __shared__ f4     et4L[D4];      // etot
    __shared__ f4     Wt4L[D4];      // Wtot = sum_h wN[h]*v_h
    __shared__ float  coefS[SS];
    __shared__ u64    maskS[SS];
    __shared__ int    cntS[SS];
    __shared__ float  ns1L[HH], ns2L[HH], ns3L[HH];
    __shared__ float  uzL[HH], wNL[HH], scL[HH], Wn3sL[HH];
    __shared__ u64    maskL[HH];
    __shared__ int    hsL[HH], hcL[HH], repL[HH], prepL[HH];
    __shared__ float  mcL[CC], ucL[CC], rZcL[CC], csL[CC], catwL[CC];
    __shared__ int    cntcL[CC];
    __shared__ int    prepStart[CC + 1];
    __shared__ int    prepSL[HH];
    __shared__ float  prepGL[HH];
    __shared__ int    clickedL[HH];
    __shared__ int    unclkL[SS];
    __shared__ int    npL, ndL, nUcnt;
    __shared__ float  PvL, vtwL, etwL, Wn3totL;

    const float* vb  = vectors + (size_t)b * HH * DD;
    const f4*    vb4 = (const f4*)vb;
    const f4*    se4 = (const f4*)subcat_embed;
    const f4*    ce4 = (const f4*)cat_embed;
    f4* o4 = (f4*)(out + (size_t)b * SS * DD);

    // ---------------- P0: ids + inits ----------------
    if (tid < HH) {
        hsL[tid] = subcategory[b * HH + tid];
        hcL[tid] = category[b * HH + tid];
    }
    for (int s = tid; s < SS; s += BLOCK) {
        coefS[s] = 1.f / (float)HH;
        maskS[s] = 0ull;
        cntS[s]  = 0;
    }
    if (tid < D4) {
        et4L[tid] = ((const f4*)pre)[tid];   // WS_ETOT == 0
        f4 z = {0.f, 0.f, 0.f, 0.f};
        vt4L[tid] = z;
        Wt4L[tid] = z;
    }
    if (tid == 0) nUcnt = 0;
    __syncthreads();

    // ---------------- A: single vb pass — 3 dots + vtot partials ----------------
    {
        const f4* wn4 = (const f4*)w_news;
        const f4* ws4 = (const f4*)w_subcat;
        const f4* wc4 = (const f4*)w_cat;
        const bool hi = lane < (D4 - 64);
        f4 vtp0 = {0.f, 0.f, 0.f, 0.f};
        f4 vtp1 = {0.f, 0.f, 0.f, 0.f};
        for (int h = wave; h < HH; h += 4) {
            f4 v0 = vb4[h * D4 + lane];
            float p1 = dot4(v0, wn4[lane]);
            float p2 = dot4(v0, ws4[lane]);
            float p3 = dot4(v0, wc4[lane]);
            vtp0 += v0;
            if (hi) {
                f4 v1 = vb4[h * D4 + 64 + lane];
                p1 += dot4(v1, wn4[64 + lane]);
                p2 += dot4(v1, ws4[64 + lane]);
                p3 += dot4(v1, wc4[64 + lane]);
                vtp1 += v1;
            }
            for (int off = 32; off; off >>= 1) {
                p1 += __shfl_down(p1, off);
                p2 += __shfl_down(p2, off);
                p3 += __shfl_down(p3, off);
            }
            if (lane == 0) { ns1L[h] = p1; ns2L[h] = p2; ns3L[h] = p3; }
        }
        float* vtf = (float*)vt4L;
        atomicAdd(&vtf[4 * lane + 0], vtp0.x);
        atomicAdd(&vtf[4 * lane + 1], vtp0.y);
        atomicAdd(&vtf[4 * lane + 2], vtp0.z);
        atomicAdd(&vtf[4 * lane + 3], vtp0.w);
        if (hi) {
            atomicAdd(&vtf[4 * (64 + lane) + 0], vtp1.x);
            atomicAdd(&vtf[4 * (64 + lane) + 1], vtp1.y);
            atomicAdd(&vtf[4 * (64 + lane) + 2], vtp1.z);
            atomicAdd(&vtf[4 * (64 + lane) + 3], vtp1.w);
        }
    }
    __syncthreads();

    // ---------------- P2: per-click stats (w0) + etw (w1) + vtw (w2) ----------
    if (tid < HH) {
        const int h = tid;
        const int s = hsL[h], c = hcL[h];
        u64 mask = 0ull, pmask = 0ull;
        for (int j = 0; j < HH; ++j) {
            bool ms = (hsL[j] == s);
            mask  |= (u64)(ms ? 1 : 0) << j;
            pmask |= (u64)((ms && hcL[j] == c) ? 1 : 0) << j;
        }
        int cnt = __popcll(mask);
        bool rep = ((__ffsll((long long)mask) - 1) == h);

        float m = FILLV;
        u64 t = mask;
        while (t) { int j = __ffsll((long long)t) - 1; t &= t - 1; m = fmaxf(m, ns1L[j]); }
        float u = expf(FILLV - m);
        float sumE = 0.f, sum2 = 0.f;
        t = mask;
        while (t) {
            int j = __ffsll((long long)t) - 1; t &= t - 1;
            float e = expf(ns1L[j] - m);
            sumE += e;
            sum2 += (e - u) * ns2L[j];
        }
        float Z = sumE + (float)(HH - cnt) * u;
        float vt2 = 0.f;
        for (int j = 0; j < HH; ++j) vt2 += ns2L[j];
        int ci = cnt < (NCC - 1) ? cnt : (NCC - 1);
        float sc = (sum2 + u * vt2) / Z + pre[WS_SCE + s] + pre[WS_CEDS + ci];

        float e_h = expf(ns1L[h] - m);
        float uz = u / Z;
        wNL[h] = (e_h - u) / Z;
        uzL[h] = uz; maskL[h] = mask; scL[h] = sc;
        repL[h]  = rep ? 1 : 0;
        prepL[h] = ((__ffsll((long long)pmask) - 1) == h) ? 1 : 0;
        if (rep) { coefS[s] = uz; maskS[s] = mask; cntS[s] = cnt; }
    } else if (wave == 1) {
        float p = 0.f;
        const float* et = (const float*)et4L;
        for (int d = lane; d < DD; d += 64) p += et[d] * w_cat[d];
        for (int off = 32; off; off >>= 1) p += __shfl_down(p, off);
        if (lane == 0) etwL = p;
    } else if (wave == 2) {
        float p = (lane < HH) ? ns3L[lane] : 0.f;
        for (int off = 32; off; off >>= 1) p += __shfl_down(p, off);
        if (lane == 0) vtwL = p;
    }
    __syncthreads();

    // ---------------- P3a: per-c stats, lists, Wn3s/Wn3tot, small outputs -----
    if (tid < CC) {
        const int c = tid;
        float mc = FILLV; int n = 0, cc2 = 0;
        for (int j = 0; j < HH; ++j) {
            if (hcL[j] == c) ++cc2;
            if (prepL[j] && hcL[j] == c) { ++n; mc = fmaxf(mc, scL[j]); }
        }
        float u = expf(FILLV - mc);
        float sumE = 0.f;
        for (int j = 0; j < HH; ++j)
            if (prepL[j] && hcL[j] == c) sumE += expf(scL[j] - mc);
        float Zc = sumE + (float)(SS - n) * u;
        mcL[c] = mc; ucL[c] = u; rZcL[c] = 1.f / Zc; cntcL[c] = cc2;
        out[OFF3 + (size_t)b * CC + c] = (float)cc2 * (1.f / (float)HH);
    } else if (tid == 64) {
        int nd = 0, np = 0;
        float sumUb = 0.f;
        for (int j = 0; j < HH; ++j) {
            if (repL[j]) { clickedL[nd] = hsL[j]; ++nd; sumUb += uzL[j]; }
            if (prepL[j]) ++np;
        }
        npL = np; ndL = nd;
        PvL = (float)(SS - nd) * (1.f / (float)HH) + sumUb;
    } else if (tid >= 128 && tid < 128 + HH) {
        const int h = tid - 128;
        float a = 0.f;
        u64 t = maskL[h];
        while (t) { int j = __ffsll((long long)t) - 1; t &= t - 1; a += wNL[j] * ns3L[j]; }
        Wn3sL[h] = a;
    } else if (wave == 3) {
        const int l = tid - 192;
        float p = (l < HH) ? wNL[l] * ns3L[l] : 0.f;
        for (int off = 32; off; off >>= 1) p += __shfl_down(p, off);
        if (l == 0) Wn3totL = p;
    }
    for (int s = tid; s < SS; s += BLOCK) {
        out[OFF1 + (size_t)b * SS + s] = (float)cntS[s] * (1.f / (float)HH);
        if (maskS[s] == 0ull) {
            int p = atomicAdd(&nUcnt, 1);
            unclkL[p] = s;
        }
    }
    __syncthreads();

    // ---------------- P3b: c-sorted prep segments + c_scores (scalar) --------
    if (tid < CC) {
        const int c = tid;
        int start = 0;
        for (int j = 0; j < HH; ++j)
            if (prepL[j] && hcL[j] < c) ++start;
        prepStart[c] = start;
        if (c == 0) prepStart[CC] = npL;
        int cur = start;
        float segs = 0.f;
        for (int j = 0; j < HH; ++j) {
            if (prepL[j] && hcL[j] == c) {
                float g = expf(scL[j] - mcL[c]) - ucL[c];
                prepSL[cur] = hsL[j]; prepGL[cur] = g;
                segs += g * (uzL[j] * vtwL + Wn3sL[j] + pre[WS_SEW + hsL[j]]);
                ++cur;
            }
        }
        int ci = cntcL[c] < (NCC - 1) ? cntcL[c] : (NCC - 1);
        csL[c] = rZcL[c] * (ucL[c] * (PvL * vtwL + etwL + Wn3totL) + segs)
                 + pre[WS_CEW + c] + pre[WS_CEDC + ci];
    }
    __syncthreads();

    // ---------------- P6b: cat softmax ----------------
    if (tid < CC) {
        float m = csL[0];
        for (int j = 1; j < CC; ++j) m = fmaxf(m, csL[j]);
        float Zc = 0.f;
        for (int j = 0; j < CC; ++j) Zc += expf(csL[j] - m);
        catwL[tid] = expf(csL[tid] - m) / Zc;
    }
    __syncthreads();

    // ---------------- D-clicked: sub_repr clicked rows + Wtot accumulation ----
    {
        const int tot = ndL * D4;
        for (int i = tid; i < tot; i += BLOCK) {
            int ii = i / D4;
            int q  = i - ii * D4;
            int s  = clickedL[ii];
            f4 wsacc = {0.f, 0.f, 0.f, 0.f};
            u64 t = maskS[s];
            while (t) {
                int j = __ffsll((long long)t) - 1; t &= t - 1;
                wsacc += wNL[j] * vb4[j * D4 + q];
            }
            float* wt = (float*)&Wt4L[q];
            atomicAdd(&wt[0], wsacc.x);
            atomicAdd(&wt[1], wsacc.y);
            atomicAdd(&wt[2], wsacc.z);
            atomicAdd(&wt[3], wsacc.w);
            f4 val = coefS[s] * vt4L[q] + wsacc + se4[s * D4 + q];
            o4[s * D4 + q] = val;    // plain store: re-read from L2 in cat phase
        }
    }
    __syncthreads();

    // ======== No more barriers: cat/user (threads<100) overlaps D-fast ========

    // ---------------- C: cat_repr + user_repr from SubTot + L2 row re-reads ---
    if (tid < D4) {
        const int q = tid;
        f4 SubTot = PvL * vt4L[q] + Wt4L[q] + et4L[q];
        f4 uacc = {0.f, 0.f, 0.f, 0.f};
        f4* oc = (f4*)(out + OFF2 + (size_t)b * CC * DD);
        for (int c = 0; c < CC; ++c) {
            f4 acc = ucL[c] * SubTot;
            const int e = prepStart[c + 1];
            for (int jj = prepStart[c]; jj < e; ++jj)
                acc += prepGL[jj] * o4[prepSL[jj] * D4 + q];
            f4 val = rZcL[c] * acc + ce4[c * D4 + q];
            uacc += catwL[c] * val;
            oc[c * D4 + q] = val;
        }
        f4* ou = (f4*)(out + OFF4 + (size_t)b * DD);
        ou[q] = uacc;
    }

    // ---------------- D-fast: unclicked rows — pure stream, 4x unrolled -------
    {
        const int tot = (SS - ndL) * D4;
        const float cst = 1.f / (float)HH;
        int i = tid;
        int u = i / D4;
        int q = i - u * D4;
        // stride BLOCK=256 advances (u,q) by (2, +56 with carry)
        #define ADV(U, Q) { (Q) += 56; (U) += 2; if ((Q) >= D4) { (Q) -= D4; ++(U); } }
        while (i + 3 * BLOCK < tot) {
            int u0 = u, q0 = q;
            int u1 = u0, q1 = q0; ADV(u1, q1);
            int u2 = u1, q2 = q1; ADV(u2, q2);
            int u3 = u2, q3 = q2; ADV(u3, q3);
            int s0 = unclkL[u0], s1 = unclkL[u1], s2 = unclkL[u2], s3 = unclkL[u3];
            f4 e0 = se4[s0 * D4 + q0];
            f4 e1 = se4[s1 * D4 + q1];
            f4 e2 = se4[s2 * D4 + q2];
            f4 e3 = se4[s3 * D4 + q3];
            f4 t0 = vt4L[q0], t1 = vt4L[q1], t2 = vt4L[q2], t3 = vt4L[q3];
            o4[s0 * D4 + q0] = cst * t0 + e0;
            o4[s1 * D4 + q1] = cst * t1 + e1;
            o4[s2 * D4 + q2] = cst * t2 + e2;
            o4[s3 * D4 + q3] = cst * t3 + e3;
            u = u3; q = q3; ADV(u, q);
            i += 4 * BLOCK;
        }
        for (; i < tot; i += BLOCK) {
            int s = unclkL[u];
            o4[s * D4 + q] = cst * vt4L[q] + se4[s * D4 + q];
            ADV(u, q);
        }
        #undef ADV
    }
}

extern "C" void kernel_launch(void* const* d_in, const int* in_sizes, int n_in,
                              void* d_out, int out_size, void* d_ws, size_t ws_size,
                              hipStream_t stream) {
    const float* vectors      = (const float*)d_in[0];
    const int*   subcategory  = (const int*)d_in[1];
    const int*   category     = (const int*)d_in[2];
    const float* subcat_embed = (const float*)d_in[3];
    const float* cat_embed    = (const float*)d_in[4];
    const float* clicks_embed = (const float*)d_in[5];
    const float* w_news       = (const float*)d_in[6];
    const float* w_subcat     = (const float*)d_in[7];
    const float* w_cat        = (const float*)d_in[8];
    float* out = (float*)d_out;
    float* ws  = (float*)d_ws;

    hipLaunchKernelGGL(hierec_pre, dim3(32), dim3(256), 0, stream,
                       subcat_embed, cat_embed, clicks_embed, w_subcat, w_cat, ws);
    hipLaunchKernelGGL(hierec_main, dim3(BB), dim3(BLOCK), 0, stream,
                       vectors, subcategory, category, subcat_embed, cat_embed,
                       w_news, w_subcat, w_cat, ws, out);
}

// Round 7
// 512.147 us; speedup vs baseline: 1.1408x; 1.1408x over previous
//
#include <hip/hip_runtime.h>

// Problem constants (match reference)
#define BB 2048
#define HH 50
#define DD 400
#define D4 100            // DD/4 float4 per row
#define SS 285
#define CC 18
#define NCC 50
#define FILLV 1e-30f

static constexpr int BLOCK = 256;

// Output offsets (elements)
static constexpr size_t OFF1 = (size_t)BB * SS * DD;            // sub_weights
static constexpr size_t OFF2 = OFF1 + (size_t)BB * SS;          // cat_repr
static constexpr size_t OFF3 = OFF2 + (size_t)BB * CC * DD;     // cat_weights
static constexpr size_t OFF4 = OFF3 + (size_t)BB * CC;          // user_repr

// d_ws layout (floats)
#define WS_ETOT 0      // 400
#define WS_SCE  400    // 285  subcat_embed[s] . w_subcat[:D]
#define WS_SEW  688    // 285  subcat_embed[s] . w_cat[:D]
#define WS_CEDS 976    // 50   clicks_embed[k] . w_subcat[D:]
#define WS_CEDC 1026   // 50   clicks_embed[k] . w_cat[D:]
#define WS_CEW  1076   // 18   cat_embed[c] . w_cat[:D]
// per-batch region (split mode)
#define WS_BATCH 1152
#define PB_BASE  0     // 400 floats: vt/50
#define PB_LIST  400   // 285 ints: unclicked s list
#define PB_NU    685   // 1 int: count
#define PB_STRIDE 688
static constexpr size_t NEEDED_WS_BYTES =
    (size_t)(WS_BATCH + (size_t)BB * PB_STRIDE) * 4;

typedef float f4 __attribute__((ext_vector_type(4)));
typedef unsigned long long u64;

__device__ __forceinline__ float dot4(f4 a, f4 b) {
    return a.x * b.x + a.y * b.y + a.z * b.z + a.w * b.w;
}

// ---------------------------------------------------------------------------
// Pre-kernel: batch-invariant precomputation into d_ws
// ---------------------------------------------------------------------------
__global__ void hierec_pre(const float* __restrict__ subcat_embed,
                           const float* __restrict__ cat_embed,
                           const float* __restrict__ clicks_embed,
                           const float* __restrict__ w_subcat,
                           const float* __restrict__ w_cat,
                           float* __restrict__ ws)
{
    const int tid  = threadIdx.x;
    const int lane = tid & 63;
    const int wave = tid >> 6;
    const int wpb  = blockDim.x >> 6;
    const int gw   = blockIdx.x * wpb + wave;
    const int nw   = gridDim.x * wpb;

    for (int s = gw; s < SS; s += nw) {
        float p1 = 0.f, p2 = 0.f;
        for (int d = lane; d < DD; d += 64) {
            float v = subcat_embed[s * DD + d];
            p1 += v * w_subcat[d];
            p2 += v * w_cat[d];
        }
        for (int off = 32; off; off >>= 1) {
            p1 += __shfl_down(p1, off);
            p2 += __shfl_down(p2, off);
        }
        if (lane == 0) { ws[WS_SCE + s] = p1; ws[WS_SEW + s] = p2; }
    }
    if (blockIdx.x == 0) {
        for (int d = tid; d < DD; d += blockDim.x) {
            float a = 0.f;
            for (int s = 0; s < SS; ++s) a += subcat_embed[s * DD + d];
            ws[WS_ETOT + d] = a;
        }
    }
    if (blockIdx.x == 1) {
        for (int k = wave; k < HH; k += wpb) {
            float p1 = 0.f, p2 = 0.f;
            if (lane < NCC) {
                float v = clicks_embed[k * NCC + lane];
                p1 = v * w_subcat[DD + lane];
                p2 = v * w_cat[DD + lane];
            }
            for (int off = 32; off; off >>= 1) {
                p1 += __shfl_down(p1, off);
                p2 += __shfl_down(p2, off);
            }
            if (lane == 0) { ws[WS_CEDS + k] = p1; ws[WS_CEDC + k] = p2; }
        }
    }
    if (blockIdx.x == 2) {
        for (int c = wave; c < CC; c += wpb) {
            float p = 0.f;
            for (int d = lane; d < DD; d += 64) p += cat_embed[c * DD + d] * w_cat[d];
            for (int off = 32; off; off >>= 1) p += __shfl_down(p, off);
            if (lane == 0) ws[WS_CEW + c] = p;
        }
    }
}

// ---------------------------------------------------------------------------
// K1: per-batch stats + clicked rows + cat/user (+ ws handoff in split mode)
// ---------------------------------------------------------------------------
__global__ __launch_bounds__(BLOCK, 8) void hierec_main(
    const float* __restrict__ vectors,      // [B,H,D]
    const int*   __restrict__ subcategory,  // [B,H]
    const int*   __restrict__ category,     // [B,H]
    const float* __restrict__ subcat_embed, // [S,D]
    const float* __restrict__ cat_embed,    // [C,D]
    const float* __restrict__ w_news,       // [D]
    const float* __restrict__ w_subcat,     // [D+NC]
    const float* __restrict__ w_cat,        // [D+NC]
    float* __restrict__ ws,                 // pre + per-batch handoff
    float* __restrict__ out,
    int split)
{
    const int b    = blockIdx.x;
    const int tid  = threadIdx.x;
    const int lane = tid & 63;
    const int wave = tid >> 6;
    const float* pre = ws;

    __shared__ f4     vt4L[D4];      // vtot
    __shared__ f4     et4L[D4];      // etot
    __shared__ f4     Wt4L[D4];      // Wtot = sum_h wN[h]*v_h
    __shared__ float  coefS[SS];
    __shared__ u64    maskS[SS];
    __shared__ int    cntS[SS];
    __shared__ float  ns1L[HH], ns2L[HH], ns3L[HH];
    __shared__ float  uzL[HH], wNL[HH], scL[HH], Wn3sL[HH];
    __shared__ u64    maskL[HH];
    __shared__ int    hsL[HH], hcL[HH], repL[HH], prepL[HH];
    __shared__ float  mcL[CC], ucL[CC], rZcL[CC], csL[CC], catwL[CC];
    __shared__ int    cntcL[CC];
    __shared__ int    prepStart[CC + 1];
    __shared__ int    prepSL[HH];
    __shared__ float  prepGL[HH];
    __shared__ int    clickedL[HH];
    __shared__ int    unclkL[SS];
    __shared__ int    npL, ndL, nUcnt;
    __shared__ float  PvL, vtwL, etwL, Wn3totL;

    const float* vb  = vectors + (size_t)b * HH * DD;
    const f4*    vb4 = (const f4*)vb;
    const f4*    se4 = (const f4*)subcat_embed;
    const f4*    ce4 = (const f4*)cat_embed;
    f4* o4 = (f4*)(out + (size_t)b * SS * DD);

    // ---------------- P0: ids + inits ----------------
    if (tid < HH) {
        hsL[tid] = subcategory[b * HH + tid];
        hcL[tid] = category[b * HH + tid];
    }
    for (int s = tid; s < SS; s += BLOCK) {
        coefS[s] = 1.f / (float)HH;
        maskS[s] = 0ull;
        cntS[s]  = 0;
    }
    if (tid < D4) {
        et4L[tid] = ((const f4*)pre)[tid];   // WS_ETOT == 0
        f4 z = {0.f, 0.f, 0.f, 0.f};
        vt4L[tid] = z;
        Wt4L[tid] = z;
    }
    if (tid == 0) nUcnt = 0;
    __syncthreads();

    // ---------------- A: single vb pass — 3 dots + vtot partials ----------------
    {
        const f4* wn4 = (const f4*)w_news;
        const f4* ws4 = (const f4*)w_subcat;
        const f4* wc4 = (const f4*)w_cat;
        const bool hi = lane < (D4 - 64);
        f4 vtp0 = {0.f, 0.f, 0.f, 0.f};
        f4 vtp1 = {0.f, 0.f, 0.f, 0.f};
        for (int h = wave; h < HH; h += 4) {
            f4 v0 = vb4[h * D4 + lane];
            float p1 = dot4(v0, wn4[lane]);
            float p2 = dot4(v0, ws4[lane]);
            float p3 = dot4(v0, wc4[lane]);
            vtp0 += v0;
            if (hi) {
                f4 v1 = vb4[h * D4 + 64 + lane];
                p1 += dot4(v1, wn4[64 + lane]);
                p2 += dot4(v1, ws4[64 + lane]);
                p3 += dot4(v1, wc4[64 + lane]);
                vtp1 += v1;
            }
            for (int off = 32; off; off >>= 1) {
                p1 += __shfl_down(p1, off);
                p2 += __shfl_down(p2, off);
                p3 += __shfl_down(p3, off);
            }
            if (lane == 0) { ns1L[h] = p1; ns2L[h] = p2; ns3L[h] = p3; }
        }
        float* vtf = (float*)vt4L;
        atomicAdd(&vtf[4 * lane + 0], vtp0.x);
        atomicAdd(&vtf[4 * lane + 1], vtp0.y);
        atomicAdd(&vtf[4 * lane + 2], vtp0.z);
        atomicAdd(&vtf[4 * lane + 3], vtp0.w);
        if (hi) {
            atomicAdd(&vtf[4 * (64 + lane) + 0], vtp1.x);
            atomicAdd(&vtf[4 * (64 + lane) + 1], vtp1.y);
            atomicAdd(&vtf[4 * (64 + lane) + 2], vtp1.z);
            atomicAdd(&vtf[4 * (64 + lane) + 3], vtp1.w);
        }
    }
    __syncthreads();

    // ---------------- P2: per-click stats (w0) + etw (w1) + vtw (w2) ----------
    if (tid < HH) {
        const int h = tid;
        const int s = hsL[h], c = hcL[h];
        u64 mask = 0ull, pmask = 0ull;
        for (int j = 0; j < HH; ++j) {
            bool ms = (hsL[j] == s);
            mask  |= (u64)(ms ? 1 : 0) << j;
            pmask |= (u64)((ms && hcL[j] == c) ? 1 : 0) << j;
        }
        int cnt = __popcll(mask);
        bool rep = ((__ffsll((long long)mask) - 1) == h);

        float m = FILLV;
        u64 t = mask;
        while (t) { int j = __ffsll((long long)t) - 1; t &= t - 1; m = fmaxf(m, ns1L[j]); }
        float u = expf(FILLV - m);
        float sumE = 0.f, sum2 = 0.f;
        t = mask;
        while (t) {
            int j = __ffsll((long long)t) - 1; t &= t - 1;
            float e = expf(ns1L[j] - m);
            sumE += e;
            sum2 += (e - u) * ns2L[j];
        }
        float Z = sumE + (float)(HH - cnt) * u;
        float vt2 = 0.f;
        for (int j = 0; j < HH; ++j) vt2 += ns2L[j];
        int ci = cnt < (NCC - 1) ? cnt : (NCC - 1);
        float sc = (sum2 + u * vt2) / Z + pre[WS_SCE + s] + pre[WS_CEDS + ci];

        float e_h = expf(ns1L[h] - m);
        float uz = u / Z;
        wNL[h] = (e_h - u) / Z;
        uzL[h] = uz; maskL[h] = mask; scL[h] = sc;
        repL[h]  = rep ? 1 : 0;
        prepL[h] = ((__ffsll((long long)pmask) - 1) == h) ? 1 : 0;
        if (rep) { coefS[s] = uz; maskS[s] = mask; cntS[s] = cnt; }
    } else if (wave == 1) {
        float p = 0.f;
        const float* et = (const float*)et4L;
        for (int d = lane; d < DD; d += 64) p += et[d] * w_cat[d];
        for (int off = 32; off; off >>= 1) p += __shfl_down(p, off);
        if (lane == 0) etwL = p;
    } else if (wave == 2) {
        float p = (lane < HH) ? ns3L[lane] : 0.f;
        for (int off = 32; off; off >>= 1) p += __shfl_down(p, off);
        if (lane == 0) vtwL = p;
    }
    __syncthreads();

    // ---------------- P3a: per-c stats, lists, Wn3s/Wn3tot, small outputs -----
    if (tid < CC) {
        const int c = tid;
        float mc = FILLV; int n = 0, cc2 = 0;
        for (int j = 0; j < HH; ++j) {
            if (hcL[j] == c) ++cc2;
            if (prepL[j] && hcL[j] == c) { ++n; mc = fmaxf(mc, scL[j]); }
        }
        float u = expf(FILLV - mc);
        float sumE = 0.f;
        for (int j = 0; j < HH; ++j)
            if (prepL[j] && hcL[j] == c) sumE += expf(scL[j] - mc);
        float Zc = sumE + (float)(SS - n) * u;
        mcL[c] = mc; ucL[c] = u; rZcL[c] = 1.f / Zc; cntcL[c] = cc2;
        __builtin_nontemporal_store((float)cc2 * (1.f / (float)HH),
                                    &out[OFF3 + (size_t)b * CC + c]);
    } else if (tid == 64) {
        int nd = 0, np = 0;
        float sumUb = 0.f;
        for (int j = 0; j < HH; ++j) {
            if (repL[j]) { clickedL[nd] = hsL[j]; ++nd; sumUb += uzL[j]; }
            if (prepL[j]) ++np;
        }
        npL = np; ndL = nd;
        PvL = (float)(SS - nd) * (1.f / (float)HH) + sumUb;
    } else if (tid >= 128 && tid < 128 + HH) {
        const int h = tid - 128;
        float a = 0.f;
        u64 t = maskL[h];
        while (t) { int j = __ffsll((long long)t) - 1; t &= t - 1; a += wNL[j] * ns3L[j]; }
        Wn3sL[h] = a;
    } else if (wave == 3) {
        const int l = tid - 192;
        float p = (l < HH) ? wNL[l] * ns3L[l] : 0.f;
        for (int off = 32; off; off >>= 1) p += __shfl_down(p, off);
        if (l == 0) Wn3totL = p;
    }
    for (int s = tid; s < SS; s += BLOCK) {
        __builtin_nontemporal_store((float)cntS[s] * (1.f / (float)HH),
                                    &out[OFF1 + (size_t)b * SS + s]);
        if (maskS[s] == 0ull) {
            int p = atomicAdd(&nUcnt, 1);
            unclkL[p] = s;
        }
    }
    __syncthreads();

    // ---------------- P3b: c-sorted prep segments + c_scores (scalar) --------
    if (tid < CC) {
        const int c = tid;
        int start = 0;
        for (int j = 0; j < HH; ++j)
            if (prepL[j] && hcL[j] < c) ++start;
        prepStart[c] = start;
        if (c == 0) prepStart[CC] = npL;
        int cur = start;
        float segs = 0.f;
        for (int j = 0; j < HH; ++j) {
            if (prepL[j] && hcL[j] == c) {
                float g = expf(scL[j] - mcL[c]) - ucL[c];
                prepSL[cur] = hsL[j]; prepGL[cur] = g;
                segs += g * (uzL[j] * vtwL + Wn3sL[j] + pre[WS_SEW + hsL[j]]);
                ++cur;
            }
        }
        int ci = cntcL[c] < (NCC - 1) ? cntcL[c] : (NCC - 1);
        csL[c] = rZcL[c] * (ucL[c] * (PvL * vtwL + etwL + Wn3totL) + segs)
                 + pre[WS_CEW + c] + pre[WS_CEDC + ci];
    }
    __syncthreads();

    // ---------------- P6b: cat softmax ----------------
    if (tid < CC) {
        float m = csL[0];
        for (int j = 1; j < CC; ++j) m = fmaxf(m, csL[j]);
        float Zc = 0.f;
        for (int j = 0; j < CC; ++j) Zc += expf(csL[j] - m);
        catwL[tid] = expf(csL[tid] - m) / Zc;
    }
    __syncthreads();

    // ---------------- D-clicked: sub_repr clicked rows + Wtot accumulation ----
    {
        const int tot = ndL * D4;
        for (int i = tid; i < tot; i += BLOCK) {
            int ii = i / D4;
            int q  = i - ii * D4;
            int s  = clickedL[ii];
            f4 wsacc = {0.f, 0.f, 0.f, 0.f};
            u64 t = maskS[s];
            while (t) {
                int j = __ffsll((long long)t) - 1; t &= t - 1;
                wsacc += wNL[j] * vb4[j * D4 + q];
            }
            float* wt = (float*)&Wt4L[q];
            atomicAdd(&wt[0], wsacc.x);
            atomicAdd(&wt[1], wsacc.y);
            atomicAdd(&wt[2], wsacc.z);
            atomicAdd(&wt[3], wsacc.w);
            f4 val = coefS[s] * vt4L[q] + wsacc + se4[s * D4 + q];
            o4[s * D4 + q] = val;    // plain store: re-read from L2 in cat phase
        }
    }
    __syncthreads();

    // ======== No more barriers ========

    // ---------------- C: cat_repr + user_repr from SubTot + L2 row re-reads ---
    if (tid < D4) {
        const int q = tid;
        f4 SubTot = PvL * vt4L[q] + Wt4L[q] + et4L[q];
        f4 uacc = {0.f, 0.f, 0.f, 0.f};
        f4* oc = (f4*)(out + OFF2 + (size_t)b * CC * DD);
        for (int c = 0; c < CC; ++c) {
            f4 acc = ucL[c] * SubTot;
            const int e = prepStart[c + 1];
            for (int jj = prepStart[c]; jj < e; ++jj)
                acc += prepGL[jj] * o4[prepSL[jj] * D4 + q];
            f4 val = rZcL[c] * acc + ce4[c * D4 + q];
            uacc += catwL[c] * val;
            __builtin_nontemporal_store(val, &oc[c * D4 + q]);
        }
        f4* ou = (f4*)(out + OFF4 + (size_t)b * DD);
        __builtin_nontemporal_store(uacc, &ou[q]);
    }

    if (split) {
        // ---------------- Handoff: base + unclk list + count to ws ------------
        float* wb = ws + WS_BATCH + (size_t)b * PB_STRIDE;
        if (tid < D4) ((f4*)wb)[tid] = (1.f / (float)HH) * vt4L[tid];
        const int nU = nUcnt;
        int* wlist = (int*)(wb + PB_LIST);
        for (int i = tid; i < nU; i += BLOCK) wlist[i] = unclkL[i];
        if (tid == 0) ((int*)(wb + PB_NU))[0] = nU;
    } else {
        // ---------------- D-fast fallback: unclicked rows — pure stream -------
        const int tot = (SS - ndL) * D4;
        const float cst = 1.f / (float)HH;
        for (int i = tid; i < tot; i += BLOCK) {
            int u = i / D4;
            int q = i - u * D4;
            int s = unclkL[u];
            f4 acc = cst * vt4L[q] + se4[s * D4 + q];
            __builtin_nontemporal_store(acc, &o4[s * D4 + q]);
        }
    }
}

// ---------------------------------------------------------------------------
// K2: pure streaming kernel — unclicked sub_repr rows = base_b + se_s
// ---------------------------------------------------------------------------
static constexpr int CHUNKS = 4;

__global__ __launch_bounds__(BLOCK, 8) void hierec_stream(
    const float* __restrict__ subcat_embed,
    const float* __restrict__ ws,
    float* __restrict__ out)
{
    const int b   = blockIdx.x / CHUNKS;
    const int ch  = blockIdx.x % CHUNKS;
    const int tid = threadIdx.x;

    __shared__ f4  baseL[D4];
    __shared__ int listL[(SS + CHUNKS - 1) / CHUNKS + 1];

    const float* wb = ws + WS_BATCH + (size_t)b * PB_STRIDE;
    if (tid < D4) baseL[tid] = ((const f4*)wb)[tid];

    const int nU  = ((const int*)(wb + PB_NU))[0];
    const int per = (nU + CHUNKS - 1) / CHUNKS;
    int r0 = ch * per; if (r0 > nU) r0 = nU;
    int r1 = r0 + per; if (r1 > nU) r1 = nU;
    const int nrows = r1 - r0;

    const int* list = (const int*)(wb + PB_LIST);
    for (int i = tid; i < nrows; i += BLOCK) listL[i] = list[r0 + i];
    __syncthreads();

    const f4* se4 = (const f4*)subcat_embed;
    f4* o4 = (f4*)(out + (size_t)b * SS * DD);
    const int items = nrows * D4;
    for (int i = tid; i < items; i += BLOCK) {
        int u = i / D4;
        int q = i - u * D4;
        int s = listL[u];
        f4 v = baseL[q] + se4[s * D4 + q];
        __builtin_nontemporal_store(v, &o4[s * D4 + q]);
    }
}

extern "C" void kernel_launch(void* const* d_in, const int* in_sizes, int n_in,
                              void* d_out, int out_size, void* d_ws, size_t ws_size,
                              hipStream_t stream) {
    const float* vectors      = (const float*)d_in[0];
    const int*   subcategory  = (const int*)d_in[1];
    const int*   category     = (const int*)d_in[2];
    const float* subcat_embed = (const float*)d_in[3];
    const float* cat_embed    = (const float*)d_in[4];
    const float* clicks_embed = (const float*)d_in[5];
    const float* w_news       = (const float*)d_in[6];
    const float* w_subcat     = (const float*)d_in[7];
    const float* w_cat        = (const float*)d_in[8];
    float* out = (float*)d_out;
    float* ws  = (float*)d_ws;

    const int split = (ws_size >= NEEDED_WS_BYTES) ? 1 : 0;

    hipLaunchKernelGGL(hierec_pre, dim3(32), dim3(256), 0, stream,
                       subcat_embed, cat_embed, clicks_embed, w_subcat, w_cat, ws);
    hipLaunchKernelGGL(hierec_main, dim3(BB), dim3(BLOCK), 0, stream,
                       vectors, subcategory, category, subcat_embed, cat_embed,
                       w_news, w_subcat, w_cat, ws, out, split);
    if (split) {
        hipLaunchKernelGGL(hierec_stream, dim3(BB * CHUNKS), dim3(BLOCK), 0, stream,
                           subcat_embed, ws, out);
    }
}